// Round 8
// baseline (488.641 us; speedup 1.0000x reference)
//
#include <hip/hip_runtime.h>
#include <hip/hip_fp16.h>
#include <math.h>

#define IN_F 256
#define NHEAD 8
#define FDIM 32
#define SCAN_B 512

typedef _Float16 f16x8 __attribute__((ext_vector_type(8)));
typedef float f32x4 __attribute__((ext_vector_type(4)));

__device__ inline unsigned pkh2(float x, float y) {
  __half2 h = __floats2half2_rn(x, y);
  return *reinterpret_cast<unsigned*>(&h);
}

// ---------------- CSR build ----------------

__global__ __launch_bounds__(256) void hist_k(const int* __restrict__ dst,
                                              int* __restrict__ deg, int E) {
  int i = blockIdx.x * 256 + threadIdx.x;
  if (i < E) atomicAdd(&deg[dst[i]], 1);
}

__global__ __launch_bounds__(SCAN_B) void scan1_k(const int* __restrict__ deg,
                                                  int* __restrict__ offs,
                                                  int* __restrict__ bsum, int N) {
  __shared__ int s[SCAN_B];
  int t = threadIdx.x;
  int i = blockIdx.x * SCAN_B + t;
  s[t] = (i < N) ? deg[i] : 0;
  __syncthreads();
  for (int off = 1; off < SCAN_B; off <<= 1) {
    int add = (t >= off) ? s[t - off] : 0;
    __syncthreads();
    s[t] += add;
    __syncthreads();
  }
  if (i < N) offs[i + 1] = s[t];
  if (t == SCAN_B - 1) bsum[blockIdx.x] = s[t];
}

__global__ __launch_bounds__(SCAN_B) void scan2_k(int* __restrict__ bsum, int nb) {
  __shared__ int s[SCAN_B];
  int t = threadIdx.x;
  s[t] = (t < nb) ? bsum[t] : 0;
  __syncthreads();
  for (int off = 1; off < SCAN_B; off <<= 1) {
    int add = (t >= off) ? s[t - off] : 0;
    __syncthreads();
    s[t] += add;
    __syncthreads();
  }
  if (t < nb) bsum[t] = (t == 0) ? 0 : s[t - 1];
}

__global__ __launch_bounds__(SCAN_B) void scan3_k(int* __restrict__ offs,
                                                  const int* __restrict__ bsum, int N) {
  int i = blockIdx.x * SCAN_B + threadIdx.x;
  if (i < N) offs[i + 1] += bsum[blockIdx.x];
  if (i == 0) offs[0] = 0;
}

__global__ __launch_bounds__(256) void scatter_k(const int* __restrict__ src,
                                                 const int* __restrict__ dst,
                                                 const int* __restrict__ offs,
                                                 int* __restrict__ cursor,
                                                 int* __restrict__ esrc, int E) {
  int i = blockIdx.x * 256 + threadIdx.x;
  if (i < E) {
    int d = dst[i];
    int pos = offs[d] + atomicAdd(&cursor[d], 1);
    esrc[pos] = src[i];
  }
}

// ---------------- W1 transpose + fp16 cast: W1t[n][k] = (half)W1[k][n] ----------------
__global__ __launch_bounds__(256) void w1cvt_k(const float* __restrict__ W1,
                                               __half* __restrict__ W1t) {
  __shared__ float s[16][17];
  int bx = blockIdx.x * 16, by = blockIdx.y * 16;
  int tx = threadIdx.x, ty = threadIdx.y;
  s[ty][tx] = W1[(by + ty) * 256 + bx + tx];
  __syncthreads();
  W1t[(size_t)(bx + ty) * 256 + by + tx] = __float2half(s[tx][ty]);
}

// ---------------- GEMM1 via MFMA, software-pipelined B, dual acc chains ----------------
// 4 waves/block, wave owns 16 rows x 256 cols. A (x fp32) converted in-register.
// B (W1t[n][k] fp16, L2-resident) double-buffered 1 nf ahead in named frags.
__global__ __launch_bounds__(256, 2) void gemm_xw_mfma_k(const float* __restrict__ X,
                                                         const __half* __restrict__ W1t,
                                                         __half* __restrict__ Zh, int M) {
  int t = threadIdx.x;
  int wv = t >> 6, l = t & 63;
  int r = l & 15, kg = l >> 4;
  int row0 = blockIdx.x * 64 + wv * 16;
  int row = row0 + r;
  int rowc = (row < M) ? row : (M - 1);

  f16x8 a[8];
  const float* xp = X + (size_t)rowc * 256 + kg * 8;
#pragma unroll
  for (int ks = 0; ks < 8; ++ks) {
    float4 f0 = *reinterpret_cast<const float4*>(xp + ks * 32);
    float4 f1 = *reinterpret_cast<const float4*>(xp + ks * 32 + 4);
    f16x8 av;
    av[0] = (_Float16)f0.x; av[1] = (_Float16)f0.y;
    av[2] = (_Float16)f0.z; av[3] = (_Float16)f0.w;
    av[4] = (_Float16)f1.x; av[5] = (_Float16)f1.y;
    av[6] = (_Float16)f1.z; av[7] = (_Float16)f1.w;
    a[ks] = av;
  }

  const __half* bbase = W1t + (size_t)r * 256 + kg * 8;  // + nf*16*256 per frag-col
  int orow = row0 + kg * 4;
  bool st_ok = (orow + 3 < M);

#define LDB(v, nfi)                                                                     \
  {                                                                                     \
    const f16x8* q = reinterpret_cast<const f16x8*>(bbase + (size_t)(nfi) * 4096);      \
    v##0 = q[0];  v##1 = q[4];  v##2 = q[8];  v##3 = q[12];                             \
    v##4 = q[16]; v##5 = q[20]; v##6 = q[24]; v##7 = q[28];                             \
  }

#define CMP(v, nfi)                                                                     \
  {                                                                                     \
    f32x4 e0 = {0.f, 0.f, 0.f, 0.f}, e1 = {0.f, 0.f, 0.f, 0.f};                         \
    e0 = __builtin_amdgcn_mfma_f32_16x16x32_f16(a[0], v##0, e0, 0, 0, 0);               \
    e1 = __builtin_amdgcn_mfma_f32_16x16x32_f16(a[1], v##1, e1, 0, 0, 0);               \
    e0 = __builtin_amdgcn_mfma_f32_16x16x32_f16(a[2], v##2, e0, 0, 0, 0);               \
    e1 = __builtin_amdgcn_mfma_f32_16x16x32_f16(a[3], v##3, e1, 0, 0, 0);               \
    e0 = __builtin_amdgcn_mfma_f32_16x16x32_f16(a[4], v##4, e0, 0, 0, 0);               \
    e1 = __builtin_amdgcn_mfma_f32_16x16x32_f16(a[5], v##5, e1, 0, 0, 0);               \
    e0 = __builtin_amdgcn_mfma_f32_16x16x32_f16(a[6], v##6, e0, 0, 0, 0);               \
    e1 = __builtin_amdgcn_mfma_f32_16x16x32_f16(a[7], v##7, e1, 0, 0, 0);               \
    f32x4 s = e0 + e1;                                                                  \
    if (st_ok) {                                                                        \
      __half2 h01 = __floats2half2_rn((float)s[0], 0.f);                                \
      Zh[(size_t)(orow + 0) * 256 + (nfi) * 16 + r] = __low2half(h01);                  \
      Zh[(size_t)(orow + 1) * 256 + (nfi) * 16 + r] = __float2half((float)s[1]);        \
      Zh[(size_t)(orow + 2) * 256 + (nfi) * 16 + r] = __float2half((float)s[2]);        \
      Zh[(size_t)(orow + 3) * 256 + (nfi) * 16 + r] = __float2half((float)s[3]);        \
    } else {                                                                            \
      for (int i = 0; i < 4; ++i)                                                       \
        if (orow + i < M)                                                               \
          Zh[(size_t)(orow + i) * 256 + (nfi) * 16 + r] = __float2half((float)s[i]);    \
    }                                                                                   \
  }

  f16x8 bA0, bA1, bA2, bA3, bA4, bA5, bA6, bA7;
  f16x8 bB0, bB1, bB2, bB3, bB4, bB5, bB6, bB7;

  LDB(bA, 0);
#pragma unroll
  for (int nf = 0; nf < 16; nf += 2) {
    LDB(bB, nf + 1);
    CMP(bA, nf);
    if (nf + 2 < 16) LDB(bA, nf + 2);
    CMP(bB, nf + 1);
  }
#undef LDB
#undef CMP
}

// ---------------- GEMM2: Zh(Mx256,fp16) = H(Mx32) @ W2(32x256) ----------------
__global__ __launch_bounds__(256) void gemm_h_k(const float* __restrict__ Hmat,
                                                const float* __restrict__ W2,
                                                __half* __restrict__ Zh, int M) {
  __shared__ float Ws[32][256];
  __shared__ float Hs[32][20];
  int t = threadIdx.x;
  for (int i = t; i < 32 * 256; i += 256) Ws[i >> 8][i & 255] = W2[i];
  int row0 = blockIdx.x * 16;
  for (int i = t; i < 16 * 32; i += 256) {
    int r = i >> 5, k = i & 31;
    Hs[k][r] = (row0 + r < M) ? Hmat[(size_t)(row0 + r) * 32 + k] : 0.f;
  }
  __syncthreads();
  int tx = t & 63, ty = t >> 6;
  float acc[4][4] = {};
#pragma unroll
  for (int k = 0; k < 32; ++k) {
    float4 a4 = *reinterpret_cast<const float4*>(&Hs[k][ty * 4]);
    float4 b4 = *reinterpret_cast<const float4*>(&Ws[k][tx * 4]);
    float a[4] = {a4.x, a4.y, a4.z, a4.w};
    float b[4] = {b4.x, b4.y, b4.z, b4.w};
#pragma unroll
    for (int i = 0; i < 4; ++i)
#pragma unroll
      for (int j = 0; j < 4; ++j) acc[i][j] = fmaf(a[i], b[j], acc[i][j]);
  }
#pragma unroll
  for (int i = 0; i < 4; ++i) {
    int r = row0 + ty * 4 + i;
    if (r < M) {
      uint2 w;
      w.x = pkh2(acc[i][0], acc[i][1]);
      w.y = pkh2(acc[i][2], acc[i][3]);
      *reinterpret_cast<uint2*>(&Zh[(size_t)r * 256 + tx * 4]) = w;
    }
  }
}

// ---------------- attention logits (fp16 z) ----------------
__global__ __launch_bounds__(256) void logits_k(const __half* __restrict__ Zh,
                                                const float* __restrict__ al,
                                                const float* __restrict__ ar,
                                                float* __restrict__ el,
                                                float* __restrict__ er, int N) {
  int wave = threadIdx.x >> 6;
  int lane = threadIdx.x & 63;
  int n = blockIdx.x * 4 + wave;
  if (n >= N) return;
  uint2 u = *reinterpret_cast<const uint2*>(&Zh[(size_t)n * 256 + lane * 4]);
  float2 f0 = __half22float2(*reinterpret_cast<__half2*>(&u.x));
  float2 f1 = __half22float2(*reinterpret_cast<__half2*>(&u.y));
  float4 a4 = reinterpret_cast<const float4*>(al)[lane];
  float4 r4 = reinterpret_cast<const float4*>(ar)[lane];
  float pl = f0.x * a4.x + f0.y * a4.y + f1.x * a4.z + f1.y * a4.w;
  float pr = f0.x * r4.x + f0.y * r4.y + f1.x * r4.z + f1.y * r4.w;
  pl += __shfl_xor(pl, 1); pl += __shfl_xor(pl, 2); pl += __shfl_xor(pl, 4);
  pr += __shfl_xor(pr, 1); pr += __shfl_xor(pr, 2); pr += __shfl_xor(pr, 4);
  if ((lane & 7) == 0) {
    int h = lane >> 3;
    el[(size_t)n * 8 + h] = pl;
    er[(size_t)n * 8 + h] = pr;
  }
}

// ---------------- per-(dst,head) softmax: unnormalized alpha + 1/denom ----------------
__global__ __launch_bounds__(256) void alpha_k(const float* __restrict__ el,
                                               const float* __restrict__ er,
                                               const int* __restrict__ offs,
                                               const int* __restrict__ esrc,
                                               float* __restrict__ alf,
                                               float* __restrict__ rden, int N) {
  int g = blockIdx.x * 256 + threadIdx.x;
  if (g >= N * NHEAD) return;
  int n = g >> 3, h = g & 7;
  int beg = offs[n], end = offs[n + 1];
  float er_h = er[g];
  float m = -INFINITY;
  for (int i = beg; i < end; ++i) {
    float e = el[(size_t)esrc[i] * 8 + h] + er_h;
    e = (e >= 0.f) ? e : 0.2f * e;
    m = fmaxf(m, e);
  }
  float s = 0.f;
  for (int i = beg; i < end; ++i) {
    float e = el[(size_t)esrc[i] * 8 + h] + er_h;
    e = (e >= 0.f) ? e : 0.2f * e;
    float ex = __expf(e - m);
    alf[(size_t)i * 8 + h] = ex;
    s += ex;
  }
  rden[g] = (end > beg) ? 1.f / s : 0.f;
}

// ---------------- per-dst aggregation: one WAVE per dst, fp16 z gather ----------------
template <bool LAYER1>
__global__ __launch_bounds__(256) void agg_k(const __half* __restrict__ Zh,
                                             const float* __restrict__ alf,
                                             const float* __restrict__ rden,
                                             const float* __restrict__ bias,
                                             const int* __restrict__ offs,
                                             const int* __restrict__ esrc,
                                             float* __restrict__ out, int N) {
  int wid = threadIdx.x >> 6, lane = threadIdx.x & 63;
  int n = blockIdx.x * 4 + wid;
  if (n >= N) return;
  int h = lane >> 3, q = lane & 7;
  int beg = offs[n], end = offs[n + 1];
  float4 acc = make_float4(0.f, 0.f, 0.f, 0.f);
#pragma unroll 4
  for (int i = beg; i < end; ++i) {
    int sidx = esrc[i];
    float a = alf[(size_t)i * 8 + h];
    uint2 u = *reinterpret_cast<const uint2*>(&Zh[(size_t)sidx * 256 + h * 32 + q * 4]);
    float2 f0 = __half22float2(*reinterpret_cast<__half2*>(&u.x));
    float2 f1 = __half22float2(*reinterpret_cast<__half2*>(&u.y));
    acc.x = fmaf(a, f0.x, acc.x);
    acc.y = fmaf(a, f0.y, acc.y);
    acc.z = fmaf(a, f1.x, acc.z);
    acc.w = fmaf(a, f1.y, acc.w);
  }
  float r = rden[(size_t)n * 8 + h];
  float4 b4 = *reinterpret_cast<const float4*>(&bias[h * 32 + q * 4]);
  float4 v;
  v.x = fmaf(acc.x, r, b4.x);
  v.y = fmaf(acc.y, r, b4.y);
  v.z = fmaf(acc.z, r, b4.z);
  v.w = fmaf(acc.w, r, b4.w);
#pragma unroll
  for (int off = 8; off < 64; off <<= 1) {
    v.x += __shfl_xor(v.x, off);
    v.y += __shfl_xor(v.y, off);
    v.z += __shfl_xor(v.z, off);
    v.w += __shfl_xor(v.w, off);
  }
  if (h == 0) {
    v.x *= 0.125f; v.y *= 0.125f; v.z *= 0.125f; v.w *= 0.125f;
    if (LAYER1) {
      v.x = (v.x > 0.f) ? v.x : expm1f(v.x);
      v.y = (v.y > 0.f) ? v.y : expm1f(v.y);
      v.z = (v.z > 0.f) ? v.z : expm1f(v.z);
      v.w = (v.w > 0.f) ? v.w : expm1f(v.w);
    }
    *reinterpret_cast<float4*>(&out[(size_t)n * 32 + q * 4]) = v;
  }
}

// ---------------- launch ----------------

extern "C" void kernel_launch(void* const* d_in, const int* in_sizes, int n_in,
                              void* d_out, int out_size, void* d_ws, size_t ws_size,
                              hipStream_t stream) {
  const float* x   = (const float*)d_in[0];
  const float* W1  = (const float*)d_in[1];
  const float* al1 = (const float*)d_in[2];
  const float* ar1 = (const float*)d_in[3];
  const float* b1  = (const float*)d_in[4];
  const float* W2  = (const float*)d_in[5];
  const float* al2 = (const float*)d_in[6];
  const float* ar2 = (const float*)d_in[7];
  const float* b2  = (const float*)d_in[8];
  const int* src   = (const int*)d_in[9];
  const int* dst   = (const int*)d_in[10];
  float* out = (float*)d_out;

  const int N = in_sizes[0] / IN_F;
  const int E = in_sizes[9];

  char* p = (char*)d_ws;
  auto alloc = [&](size_t bytes) {
    char* q = p;
    p += (bytes + 255) & ~(size_t)255;
    return q;
  };
  __half* zh  = (__half*)alloc((size_t)N * 256 * 2);  // z1 fp16, reused as z2
  __half* w1t = (__half*)alloc((size_t)256 * 256 * 2);
  float* el   = (float*)alloc((size_t)N * 8 * 4);
  float* er   = (float*)alloc((size_t)N * 8 * 4);
  float* h1   = (float*)alloc((size_t)N * 32 * 4);
  float* alf  = (float*)alloc((size_t)E * 8 * 4);
  float* rden = (float*)alloc((size_t)N * 8 * 4);
  int* offs   = (int*)alloc((size_t)(N + 1) * 4);
  int* deg    = (int*)alloc((size_t)N * 4);
  int* cursor = (int*)alloc((size_t)N * 4);
  int* bsum   = (int*)alloc((size_t)SCAN_B * 4);
  int* esrc   = (int*)alloc((size_t)E * 4);

  hipMemsetAsync(deg, 0, (size_t)N * 4, stream);
  hipMemsetAsync(cursor, 0, (size_t)N * 4, stream);

  int nb = (N + SCAN_B - 1) / SCAN_B;
  hist_k<<<(E + 255) / 256, 256, 0, stream>>>(dst, deg, E);
  scan1_k<<<nb, SCAN_B, 0, stream>>>(deg, offs, bsum, N);
  scan2_k<<<1, SCAN_B, 0, stream>>>(bsum, nb);
  scan3_k<<<nb, SCAN_B, 0, stream>>>(offs, bsum, N);
  scatter_k<<<(E + 255) / 256, 256, 0, stream>>>(src, dst, offs, cursor, esrc, E);

  int nh_blocks = (N * NHEAD + 255) / 256;

  // ---- layer 1 ----
  w1cvt_k<<<dim3(16, 16), dim3(16, 16), 0, stream>>>(W1, w1t);
  gemm_xw_mfma_k<<<(N + 63) / 64, 256, 0, stream>>>(x, w1t, zh, N);
  logits_k<<<(N + 3) / 4, 256, 0, stream>>>(zh, al1, ar1, el, er, N);
  alpha_k<<<nh_blocks, 256, 0, stream>>>(el, er, offs, esrc, alf, rden, N);
  agg_k<true><<<(N + 3) / 4, 256, 0, stream>>>(zh, alf, rden, b1, offs, esrc, h1, N);

  // ---- layer 2 ----
  gemm_h_k<<<(N + 15) / 16, 256, 0, stream>>>(h1, W2, zh, N);
  logits_k<<<(N + 3) / 4, 256, 0, stream>>>(zh, al2, ar2, el, er, N);
  alpha_k<<<nh_blocks, 256, 0, stream>>>(el, er, offs, esrc, alf, rden, N);
  agg_k<false><<<(N + 3) / 4, 256, 0, stream>>>(zh, alf, rden, b2, offs, esrc, out, N);
}

// Round 10
// 439.201 us; speedup vs baseline: 1.1126x; 1.1126x over previous
//
#include <hip/hip_runtime.h>
#include <hip/hip_fp16.h>
#include <math.h>

#define IN_F 256
#define NHEAD 8
#define FDIM 32
#define SCAN_B 512

typedef _Float16 f16x8 __attribute__((ext_vector_type(8)));
typedef float f32x4 __attribute__((ext_vector_type(4)));

__device__ inline unsigned pkh2(float x, float y) {
  __half2 h = __floats2half2_rn(x, y);
  return *reinterpret_cast<unsigned*>(&h);
}

// ---------------- CSR build ----------------

__global__ __launch_bounds__(256) void hist_k(const int* __restrict__ dst,
                                              int* __restrict__ deg, int E) {
  int i = blockIdx.x * 256 + threadIdx.x;
  if (i < E) atomicAdd(&deg[dst[i]], 1);
}

__global__ __launch_bounds__(SCAN_B) void scan1_k(const int* __restrict__ deg,
                                                  int* __restrict__ offs,
                                                  int* __restrict__ bsum, int N) {
  __shared__ int s[SCAN_B];
  int t = threadIdx.x;
  int i = blockIdx.x * SCAN_B + t;
  s[t] = (i < N) ? deg[i] : 0;
  __syncthreads();
  for (int off = 1; off < SCAN_B; off <<= 1) {
    int add = (t >= off) ? s[t - off] : 0;
    __syncthreads();
    s[t] += add;
    __syncthreads();
  }
  if (i < N) offs[i + 1] = s[t];
  if (t == SCAN_B - 1) bsum[blockIdx.x] = s[t];
}

__global__ __launch_bounds__(SCAN_B) void scan2_k(int* __restrict__ bsum, int nb) {
  __shared__ int s[SCAN_B];
  int t = threadIdx.x;
  s[t] = (t < nb) ? bsum[t] : 0;
  __syncthreads();
  for (int off = 1; off < SCAN_B; off <<= 1) {
    int add = (t >= off) ? s[t - off] : 0;
    __syncthreads();
    s[t] += add;
    __syncthreads();
  }
  if (t < nb) bsum[t] = (t == 0) ? 0 : s[t - 1];
}

__global__ __launch_bounds__(SCAN_B) void scan3_k(int* __restrict__ offs,
                                                  const int* __restrict__ bsum, int N) {
  int i = blockIdx.x * SCAN_B + threadIdx.x;
  if (i < N) offs[i + 1] += bsum[blockIdx.x];
  if (i == 0) offs[0] = 0;
}

__global__ __launch_bounds__(256) void scatter_k(const int* __restrict__ src,
                                                 const int* __restrict__ dst,
                                                 const int* __restrict__ offs,
                                                 int* __restrict__ cursor,
                                                 int* __restrict__ esrc, int E) {
  int i = blockIdx.x * 256 + threadIdx.x;
  if (i < E) {
    int d = dst[i];
    int pos = offs[d] + atomicAdd(&cursor[d], 1);
    esrc[pos] = src[i];
  }
}

// ---------------- W1 transpose + fp16 cast: W1t[n][k] = (half)W1[k][n] ----------------
__global__ __launch_bounds__(256) void w1cvt_k(const float* __restrict__ W1,
                                               __half* __restrict__ W1t) {
  __shared__ float s[16][17];
  int bx = blockIdx.x * 16, by = blockIdx.y * 16;
  int tx = threadIdx.x, ty = threadIdx.y;
  s[ty][tx] = W1[(by + ty) * 256 + bx + tx];
  __syncthreads();
  W1t[(size_t)(bx + ty) * 256 + by + tx] = __float2half(s[tx][ty]);
}

// ---------------- GEMM1 via MFMA, FULL W1t staged in 128KB LDS ----------------
// 512 threads = 8 waves, wave owns 32 rows (2 row-frags) x all 256 cols.
// W re-read from global eliminated: 400MB -> 25MB (was L3-BW bound at ~73us).
// LDS layout: [col][k] halves, 16B granules XOR-swizzled (g ^= col&31) so the
// per-nf ds_read_b128 (16 lanes @ 512B stride) hits all banks evenly.
__global__ __launch_bounds__(512, 1) void gemm_xw_mfma_k(const float* __restrict__ X,
                                                         const __half* __restrict__ W1t,
                                                         __half* __restrict__ Zh, int M) {
  __shared__ __half Ws[256 * 256];  // 128 KB
  int t = threadIdx.x;

  // ---- stage W1t -> LDS (coalesced 16B chunks), swizzled ----
#pragma unroll
  for (int i = 0; i < 16; ++i) {
    int chunk = t + i * 512;        // 0..8191
    int col = chunk >> 5;           // 0..255
    int g = chunk & 31;             // 16B granule within the 512B col-row
    f16x8 v = *reinterpret_cast<const f16x8*>(W1t + (size_t)col * 256 + g * 8);
    int gs = g ^ (col & 31);
    *reinterpret_cast<f16x8*>(&Ws[col * 256 + gs * 8]) = v;
  }

  int wid = t >> 6, l = t & 63;
  int r = l & 15, kg = l >> 4;
  int row0 = blockIdx.x * 256 + wid * 32;

  // ---- A: 2 row-frags x 8 ks, fp32 -> fp16 in-register (issued pre-barrier) ----
  int rowA0 = row0 + r;
  int rowA1 = row0 + 16 + r;
  int rc0 = (rowA0 < M) ? rowA0 : (M - 1);
  int rc1 = (rowA1 < M) ? rowA1 : (M - 1);
  const float* xp0 = X + (size_t)rc0 * 256 + kg * 8;
  const float* xp1 = X + (size_t)rc1 * 256 + kg * 8;
  f16x8 a0[8], a1[8];
#pragma unroll
  for (int ks = 0; ks < 8; ++ks) {
    float4 f0 = *reinterpret_cast<const float4*>(xp0 + ks * 32);
    float4 f1 = *reinterpret_cast<const float4*>(xp0 + ks * 32 + 4);
    f16x8 av;
    av[0] = (_Float16)f0.x; av[1] = (_Float16)f0.y;
    av[2] = (_Float16)f0.z; av[3] = (_Float16)f0.w;
    av[4] = (_Float16)f1.x; av[5] = (_Float16)f1.y;
    av[6] = (_Float16)f1.z; av[7] = (_Float16)f1.w;
    a0[ks] = av;
    float4 g0 = *reinterpret_cast<const float4*>(xp1 + ks * 32);
    float4 g1 = *reinterpret_cast<const float4*>(xp1 + ks * 32 + 4);
    f16x8 bv;
    bv[0] = (_Float16)g0.x; bv[1] = (_Float16)g0.y;
    bv[2] = (_Float16)g0.z; bv[3] = (_Float16)g0.w;
    bv[4] = (_Float16)g1.x; bv[5] = (_Float16)g1.y;
    bv[6] = (_Float16)g1.z; bv[7] = (_Float16)g1.w;
    a1[ks] = bv;
  }

  __syncthreads();

  int orow0 = row0 + kg * 4;        // rf0 output rows
  int orow1 = row0 + 16 + kg * 4;   // rf1 output rows

#pragma unroll
  for (int nf = 0; nf < 16; ++nf) {
    int colb = nf * 16 + r;
    int cbase = colb * 256;
    int cx = colb & 31;
    f16x8 b0 = *reinterpret_cast<const f16x8*>(&Ws[cbase + ((0 * 4 + kg) ^ cx) * 8]);
    f16x8 b1 = *reinterpret_cast<const f16x8*>(&Ws[cbase + ((1 * 4 + kg) ^ cx) * 8]);
    f16x8 b2 = *reinterpret_cast<const f16x8*>(&Ws[cbase + ((2 * 4 + kg) ^ cx) * 8]);
    f16x8 b3 = *reinterpret_cast<const f16x8*>(&Ws[cbase + ((3 * 4 + kg) ^ cx) * 8]);
    f16x8 b4 = *reinterpret_cast<const f16x8*>(&Ws[cbase + ((4 * 4 + kg) ^ cx) * 8]);
    f16x8 b5 = *reinterpret_cast<const f16x8*>(&Ws[cbase + ((5 * 4 + kg) ^ cx) * 8]);
    f16x8 b6 = *reinterpret_cast<const f16x8*>(&Ws[cbase + ((6 * 4 + kg) ^ cx) * 8]);
    f16x8 b7 = *reinterpret_cast<const f16x8*>(&Ws[cbase + ((7 * 4 + kg) ^ cx) * 8]);

    f32x4 e0 = {0.f, 0.f, 0.f, 0.f}, e1 = {0.f, 0.f, 0.f, 0.f};
    f32x4 f0 = {0.f, 0.f, 0.f, 0.f}, f1 = {0.f, 0.f, 0.f, 0.f};
    e0 = __builtin_amdgcn_mfma_f32_16x16x32_f16(a0[0], b0, e0, 0, 0, 0);
    e1 = __builtin_amdgcn_mfma_f32_16x16x32_f16(a0[1], b1, e1, 0, 0, 0);
    f0 = __builtin_amdgcn_mfma_f32_16x16x32_f16(a1[0], b0, f0, 0, 0, 0);
    f1 = __builtin_amdgcn_mfma_f32_16x16x32_f16(a1[1], b1, f1, 0, 0, 0);
    e0 = __builtin_amdgcn_mfma_f32_16x16x32_f16(a0[2], b2, e0, 0, 0, 0);
    e1 = __builtin_amdgcn_mfma_f32_16x16x32_f16(a0[3], b3, e1, 0, 0, 0);
    f0 = __builtin_amdgcn_mfma_f32_16x16x32_f16(a1[2], b2, f0, 0, 0, 0);
    f1 = __builtin_amdgcn_mfma_f32_16x16x32_f16(a1[3], b3, f1, 0, 0, 0);
    e0 = __builtin_amdgcn_mfma_f32_16x16x32_f16(a0[4], b4, e0, 0, 0, 0);
    e1 = __builtin_amdgcn_mfma_f32_16x16x32_f16(a0[5], b5, e1, 0, 0, 0);
    f0 = __builtin_amdgcn_mfma_f32_16x16x32_f16(a1[4], b4, f0, 0, 0, 0);
    f1 = __builtin_amdgcn_mfma_f32_16x16x32_f16(a1[5], b5, f1, 0, 0, 0);
    e0 = __builtin_amdgcn_mfma_f32_16x16x32_f16(a0[6], b6, e0, 0, 0, 0);
    e1 = __builtin_amdgcn_mfma_f32_16x16x32_f16(a0[7], b7, e1, 0, 0, 0);
    f0 = __builtin_amdgcn_mfma_f32_16x16x32_f16(a1[6], b6, f0, 0, 0, 0);
    f1 = __builtin_amdgcn_mfma_f32_16x16x32_f16(a1[7], b7, f1, 0, 0, 0);
    f32x4 s0 = e0 + e1;
    f32x4 s1 = f0 + f1;
#pragma unroll
    for (int i = 0; i < 4; ++i) {
      if (orow0 + i < M)
        Zh[(size_t)(orow0 + i) * 256 + nf * 16 + r] = __float2half((float)s0[i]);
    }
#pragma unroll
    for (int i = 0; i < 4; ++i) {
      if (orow1 + i < M)
        Zh[(size_t)(orow1 + i) * 256 + nf * 16 + r] = __float2half((float)s1[i]);
    }
  }
}

// ---------------- GEMM2: Zh(Mx256,fp16) = H(Mx32) @ W2(32x256) ----------------
__global__ __launch_bounds__(256) void gemm_h_k(const float* __restrict__ Hmat,
                                                const float* __restrict__ W2,
                                                __half* __restrict__ Zh, int M) {
  __shared__ float Ws[32][256];
  __shared__ float Hs[32][20];
  int t = threadIdx.x;
  for (int i = t; i < 32 * 256; i += 256) Ws[i >> 8][i & 255] = W2[i];
  int row0 = blockIdx.x * 16;
  for (int i = t; i < 16 * 32; i += 256) {
    int r = i >> 5, k = i & 31;
    Hs[k][r] = (row0 + r < M) ? Hmat[(size_t)(row0 + r) * 32 + k] : 0.f;
  }
  __syncthreads();
  int tx = t & 63, ty = t >> 6;
  float acc[4][4] = {};
#pragma unroll
  for (int k = 0; k < 32; ++k) {
    float4 a4 = *reinterpret_cast<const float4*>(&Hs[k][ty * 4]);
    float4 b4 = *reinterpret_cast<const float4*>(&Ws[k][tx * 4]);
    float a[4] = {a4.x, a4.y, a4.z, a4.w};
    float b[4] = {b4.x, b4.y, b4.z, b4.w};
#pragma unroll
    for (int i = 0; i < 4; ++i)
#pragma unroll
      for (int j = 0; j < 4; ++j) acc[i][j] = fmaf(a[i], b[j], acc[i][j]);
  }
#pragma unroll
  for (int i = 0; i < 4; ++i) {
    int r = row0 + ty * 4 + i;
    if (r < M) {
      uint2 w;
      w.x = pkh2(acc[i][0], acc[i][1]);
      w.y = pkh2(acc[i][2], acc[i][3]);
      *reinterpret_cast<uint2*>(&Zh[(size_t)r * 256 + tx * 4]) = w;
    }
  }
}

// ---------------- attention logits (fp16 z) ----------------
__global__ __launch_bounds__(256) void logits_k(const __half* __restrict__ Zh,
                                                const float* __restrict__ al,
                                                const float* __restrict__ ar,
                                                float* __restrict__ el,
                                                float* __restrict__ er, int N) {
  int wave = threadIdx.x >> 6;
  int lane = threadIdx.x & 63;
  int n = blockIdx.x * 4 + wave;
  if (n >= N) return;
  uint2 u = *reinterpret_cast<const uint2*>(&Zh[(size_t)n * 256 + lane * 4]);
  float2 f0 = __half22float2(*reinterpret_cast<__half2*>(&u.x));
  float2 f1 = __half22float2(*reinterpret_cast<__half2*>(&u.y));
  float4 a4 = reinterpret_cast<const float4*>(al)[lane];
  float4 r4 = reinterpret_cast<const float4*>(ar)[lane];
  float pl = f0.x * a4.x + f0.y * a4.y + f1.x * a4.z + f1.y * a4.w;
  float pr = f0.x * r4.x + f0.y * r4.y + f1.x * r4.z + f1.y * r4.w;
  pl += __shfl_xor(pl, 1); pl += __shfl_xor(pl, 2); pl += __shfl_xor(pl, 4);
  pr += __shfl_xor(pr, 1); pr += __shfl_xor(pr, 2); pr += __shfl_xor(pr, 4);
  if ((lane & 7) == 0) {
    int h = lane >> 3;
    el[(size_t)n * 8 + h] = pl;
    er[(size_t)n * 8 + h] = pr;
  }
}

// ---------------- per-(dst,head) softmax: unnormalized alpha + 1/denom ----------------
__global__ __launch_bounds__(256) void alpha_k(const float* __restrict__ el,
                                               const float* __restrict__ er,
                                               const int* __restrict__ offs,
                                               const int* __restrict__ esrc,
                                               float* __restrict__ alf,
                                               float* __restrict__ rden, int N) {
  int g = blockIdx.x * 256 + threadIdx.x;
  if (g >= N * NHEAD) return;
  int n = g >> 3, h = g & 7;
  int beg = offs[n], end = offs[n + 1];
  float er_h = er[g];
  float m = -INFINITY;
  for (int i = beg; i < end; ++i) {
    float e = el[(size_t)esrc[i] * 8 + h] + er_h;
    e = (e >= 0.f) ? e : 0.2f * e;
    m = fmaxf(m, e);
  }
  float s = 0.f;
  for (int i = beg; i < end; ++i) {
    float e = el[(size_t)esrc[i] * 8 + h] + er_h;
    e = (e >= 0.f) ? e : 0.2f * e;
    float ex = __expf(e - m);
    alf[(size_t)i * 8 + h] = ex;
    s += ex;
  }
  rden[g] = (end > beg) ? 1.f / s : 0.f;
}

// ---------------- per-dst aggregation: one WAVE per dst, fp16 z gather ----------------
template <bool LAYER1>
__global__ __launch_bounds__(256) void agg_k(const __half* __restrict__ Zh,
                                             const float* __restrict__ alf,
                                             const float* __restrict__ rden,
                                             const float* __restrict__ bias,
                                             const int* __restrict__ offs,
                                             const int* __restrict__ esrc,
                                             float* __restrict__ out, int N) {
  int wid = threadIdx.x >> 6, lane = threadIdx.x & 63;
  int n = blockIdx.x * 4 + wid;
  if (n >= N) return;
  int h = lane >> 3, q = lane & 7;
  int beg = offs[n], end = offs[n + 1];
  float4 acc = make_float4(0.f, 0.f, 0.f, 0.f);
#pragma unroll 4
  for (int i = beg; i < end; ++i) {
    int sidx = esrc[i];
    float a = alf[(size_t)i * 8 + h];
    uint2 u = *reinterpret_cast<const uint2*>(&Zh[(size_t)sidx * 256 + h * 32 + q * 4]);
    float2 f0 = __half22float2(*reinterpret_cast<__half2*>(&u.x));
    float2 f1 = __half22float2(*reinterpret_cast<__half2*>(&u.y));
    acc.x = fmaf(a, f0.x, acc.x);
    acc.y = fmaf(a, f0.y, acc.y);
    acc.z = fmaf(a, f1.x, acc.z);
    acc.w = fmaf(a, f1.y, acc.w);
  }
  float r = rden[(size_t)n * 8 + h];
  float4 b4 = *reinterpret_cast<const float4*>(&bias[h * 32 + q * 4]);
  float4 v;
  v.x = fmaf(acc.x, r, b4.x);
  v.y = fmaf(acc.y, r, b4.y);
  v.z = fmaf(acc.z, r, b4.z);
  v.w = fmaf(acc.w, r, b4.w);
#pragma unroll
  for (int off = 8; off < 64; off <<= 1) {
    v.x += __shfl_xor(v.x, off);
    v.y += __shfl_xor(v.y, off);
    v.z += __shfl_xor(v.z, off);
    v.w += __shfl_xor(v.w, off);
  }
  if (h == 0) {
    v.x *= 0.125f; v.y *= 0.125f; v.z *= 0.125f; v.w *= 0.125f;
    if (LAYER1) {
      v.x = (v.x > 0.f) ? v.x : expm1f(v.x);
      v.y = (v.y > 0.f) ? v.y : expm1f(v.y);
      v.z = (v.z > 0.f) ? v.z : expm1f(v.z);
      v.w = (v.w > 0.f) ? v.w : expm1f(v.w);
    }
    *reinterpret_cast<float4*>(&out[(size_t)n * 32 + q * 4]) = v;
  }
}

// ---------------- launch ----------------

extern "C" void kernel_launch(void* const* d_in, const int* in_sizes, int n_in,
                              void* d_out, int out_size, void* d_ws, size_t ws_size,
                              hipStream_t stream) {
  const float* x   = (const float*)d_in[0];
  const float* W1  = (const float*)d_in[1];
  const float* al1 = (const float*)d_in[2];
  const float* ar1 = (const float*)d_in[3];
  const float* b1  = (const float*)d_in[4];
  const float* W2  = (const float*)d_in[5];
  const float* al2 = (const float*)d_in[6];
  const float* ar2 = (const float*)d_in[7];
  const float* b2  = (const float*)d_in[8];
  const int* src   = (const int*)d_in[9];
  const int* dst   = (const int*)d_in[10];
  float* out = (float*)d_out;

  const int N = in_sizes[0] / IN_F;
  const int E = in_sizes[9];

  char* p = (char*)d_ws;
  auto alloc = [&](size_t bytes) {
    char* q = p;
    p += (bytes + 255) & ~(size_t)255;
    return q;
  };
  __half* zh  = (__half*)alloc((size_t)N * 256 * 2);  // z1 fp16, reused as z2
  __half* w1t = (__half*)alloc((size_t)256 * 256 * 2);
  float* el   = (float*)alloc((size_t)N * 8 * 4);
  float* er   = (float*)alloc((size_t)N * 8 * 4);
  float* h1   = (float*)alloc((size_t)N * 32 * 4);
  float* alf  = (float*)alloc((size_t)E * 8 * 4);
  float* rden = (float*)alloc((size_t)N * 8 * 4);
  int* offs   = (int*)alloc((size_t)(N + 1) * 4);
  int* deg    = (int*)alloc((size_t)N * 4);
  int* cursor = (int*)alloc((size_t)N * 4);
  int* bsum   = (int*)alloc((size_t)SCAN_B * 4);
  int* esrc   = (int*)alloc((size_t)E * 4);

  hipMemsetAsync(deg, 0, (size_t)N * 4, stream);
  hipMemsetAsync(cursor, 0, (size_t)N * 4, stream);

  int nb = (N + SCAN_B - 1) / SCAN_B;
  hist_k<<<(E + 255) / 256, 256, 0, stream>>>(dst, deg, E);
  scan1_k<<<nb, SCAN_B, 0, stream>>>(deg, offs, bsum, N);
  scan2_k<<<1, SCAN_B, 0, stream>>>(bsum, nb);
  scan3_k<<<nb, SCAN_B, 0, stream>>>(offs, bsum, N);
  scatter_k<<<(E + 255) / 256, 256, 0, stream>>>(src, dst, offs, cursor, esrc, E);

  int nh_blocks = (N * NHEAD + 255) / 256;

  // ---- layer 1 ----
  w1cvt_k<<<dim3(16, 16), dim3(16, 16), 0, stream>>>(W1, w1t);
  gemm_xw_mfma_k<<<(N + 255) / 256, 512, 0, stream>>>(x, w1t, zh, N);
  logits_k<<<(N + 3) / 4, 256, 0, stream>>>(zh, al1, ar1, el, er, N);
  alpha_k<<<nh_blocks, 256, 0, stream>>>(el, er, offs, esrc, alf, rden, N);
  agg_k<true><<<(N + 3) / 4, 256, 0, stream>>>(zh, alf, rden, b1, offs, esrc, h1, N);

  // ---- layer 2 ----
  gemm_h_k<<<(N + 15) / 16, 256, 0, stream>>>(h1, W2, zh, N);
  logits_k<<<(N + 3) / 4, 256, 0, stream>>>(zh, al2, ar2, el, er, N);
  alpha_k<<<nh_blocks, 256, 0, stream>>>(el, er, offs, esrc, alf, rden, N);
  agg_k<false><<<(N + 3) / 4, 256, 0, stream>>>(zh, alf, rden, b2, offs, esrc, out, N);
}

// Round 15
// 421.475 us; speedup vs baseline: 1.1594x; 1.0421x over previous
//
#include <hip/hip_runtime.h>
#include <hip/hip_fp16.h>
#include <math.h>

#define IN_F 256
#define NHEAD 8
#define FDIM 32
#define SCAN_B 512

typedef _Float16 f16x8 __attribute__((ext_vector_type(8)));
typedef float f32x4 __attribute__((ext_vector_type(4)));

__device__ inline unsigned pkh2(float x, float y) {
  __half2 h = __floats2half2_rn(x, y);
  return *reinterpret_cast<unsigned*>(&h);
}

// ---------------- CSR build ----------------

__global__ __launch_bounds__(256) void hist_k(const int* __restrict__ dst,
                                              int* __restrict__ deg, int E) {
  int i = blockIdx.x * 256 + threadIdx.x;
  if (i < E) atomicAdd(&deg[dst[i]], 1);
}

__global__ __launch_bounds__(SCAN_B) void scan1_k(const int* __restrict__ deg,
                                                  int* __restrict__ offs,
                                                  int* __restrict__ bsum, int N) {
  __shared__ int s[SCAN_B];
  int t = threadIdx.x;
  int i = blockIdx.x * SCAN_B + t;
  s[t] = (i < N) ? deg[i] : 0;
  __syncthreads();
  for (int off = 1; off < SCAN_B; off <<= 1) {
    int add = (t >= off) ? s[t - off] : 0;
    __syncthreads();
    s[t] += add;
    __syncthreads();
  }
  if (i < N) offs[i + 1] = s[t];
  if (t == SCAN_B - 1) bsum[blockIdx.x] = s[t];
}

__global__ __launch_bounds__(SCAN_B) void scan2_k(int* __restrict__ bsum, int nb) {
  __shared__ int s[SCAN_B];
  int t = threadIdx.x;
  s[t] = (t < nb) ? bsum[t] : 0;
  __syncthreads();
  for (int off = 1; off < SCAN_B; off <<= 1) {
    int add = (t >= off) ? s[t - off] : 0;
    __syncthreads();
    s[t] += add;
    __syncthreads();
  }
  if (t < nb) bsum[t] = (t == 0) ? 0 : s[t - 1];
}

__global__ __launch_bounds__(SCAN_B) void scan3_k(int* __restrict__ offs,
                                                  const int* __restrict__ bsum, int N) {
  int i = blockIdx.x * SCAN_B + threadIdx.x;
  if (i < N) offs[i + 1] += bsum[blockIdx.x];
  if (i == 0) offs[0] = 0;
}

__global__ __launch_bounds__(256) void scatter_k(const int* __restrict__ src,
                                                 const int* __restrict__ dst,
                                                 const int* __restrict__ offs,
                                                 int* __restrict__ cursor,
                                                 int* __restrict__ esrc, int E) {
  int i = blockIdx.x * 256 + threadIdx.x;
  if (i < E) {
    int d = dst[i];
    int pos = offs[d] + atomicAdd(&cursor[d], 1);
    esrc[pos] = src[i];
  }
}

// ---------------- W1 transpose + fp16 cast: W1t[n][k] = (half)W1[k][n] ----------------
__global__ __launch_bounds__(256) void w1cvt_k(const float* __restrict__ W1,
                                               __half* __restrict__ W1t) {
  __shared__ float s[16][17];
  int bx = blockIdx.x * 16, by = blockIdx.y * 16;
  int tx = threadIdx.x, ty = threadIdx.y;
  s[ty][tx] = W1[(by + ty) * 256 + bx + tx];
  __syncthreads();
  W1t[(size_t)(bx + ty) * 256 + by + tx] = __float2half(s[tx][ty]);
}

// ---------------- GEMM1 via MFMA, FULL W1t staged in 128KB LDS ----------------
__global__ __launch_bounds__(512, 1) void gemm_xw_mfma_k(const float* __restrict__ X,
                                                         const __half* __restrict__ W1t,
                                                         __half* __restrict__ Zh, int M) {
  __shared__ __half Ws[256 * 256];  // 128 KB
  int t = threadIdx.x;

#pragma unroll
  for (int i = 0; i < 16; ++i) {
    int chunk = t + i * 512;
    int col = chunk >> 5;
    int g = chunk & 31;
    f16x8 v = *reinterpret_cast<const f16x8*>(W1t + (size_t)col * 256 + g * 8);
    int gs = g ^ (col & 31);
    *reinterpret_cast<f16x8*>(&Ws[col * 256 + gs * 8]) = v;
  }

  int wid = t >> 6, l = t & 63;
  int r = l & 15, kg = l >> 4;
  int row0 = blockIdx.x * 256 + wid * 32;

  int rowA0 = row0 + r;
  int rowA1 = row0 + 16 + r;
  int rc0 = (rowA0 < M) ? rowA0 : (M - 1);
  int rc1 = (rowA1 < M) ? rowA1 : (M - 1);
  const float* xp0 = X + (size_t)rc0 * 256 + kg * 8;
  const float* xp1 = X + (size_t)rc1 * 256 + kg * 8;
  f16x8 a0[8], a1[8];
#pragma unroll
  for (int ks = 0; ks < 8; ++ks) {
    float4 f0 = *reinterpret_cast<const float4*>(xp0 + ks * 32);
    float4 f1 = *reinterpret_cast<const float4*>(xp0 + ks * 32 + 4);
    f16x8 av;
    av[0] = (_Float16)f0.x; av[1] = (_Float16)f0.y;
    av[2] = (_Float16)f0.z; av[3] = (_Float16)f0.w;
    av[4] = (_Float16)f1.x; av[5] = (_Float16)f1.y;
    av[6] = (_Float16)f1.z; av[7] = (_Float16)f1.w;
    a0[ks] = av;
    float4 g0 = *reinterpret_cast<const float4*>(xp1 + ks * 32);
    float4 g1 = *reinterpret_cast<const float4*>(xp1 + ks * 32 + 4);
    f16x8 bv;
    bv[0] = (_Float16)g0.x; bv[1] = (_Float16)g0.y;
    bv[2] = (_Float16)g0.z; bv[3] = (_Float16)g0.w;
    bv[4] = (_Float16)g1.x; bv[5] = (_Float16)g1.y;
    bv[6] = (_Float16)g1.z; bv[7] = (_Float16)g1.w;
    a1[ks] = bv;
  }

  __syncthreads();

  int orow0 = row0 + kg * 4;
  int orow1 = row0 + 16 + kg * 4;

#pragma unroll
  for (int nf = 0; nf < 16; ++nf) {
    int colb = nf * 16 + r;
    int cbase = colb * 256;
    int cx = colb & 31;
    f16x8 b0 = *reinterpret_cast<const f16x8*>(&Ws[cbase + ((0 * 4 + kg) ^ cx) * 8]);
    f16x8 b1 = *reinterpret_cast<const f16x8*>(&Ws[cbase + ((1 * 4 + kg) ^ cx) * 8]);
    f16x8 b2 = *reinterpret_cast<const f16x8*>(&Ws[cbase + ((2 * 4 + kg) ^ cx) * 8]);
    f16x8 b3 = *reinterpret_cast<const f16x8*>(&Ws[cbase + ((3 * 4 + kg) ^ cx) * 8]);
    f16x8 b4 = *reinterpret_cast<const f16x8*>(&Ws[cbase + ((4 * 4 + kg) ^ cx) * 8]);
    f16x8 b5 = *reinterpret_cast<const f16x8*>(&Ws[cbase + ((5 * 4 + kg) ^ cx) * 8]);
    f16x8 b6 = *reinterpret_cast<const f16x8*>(&Ws[cbase + ((6 * 4 + kg) ^ cx) * 8]);
    f16x8 b7 = *reinterpret_cast<const f16x8*>(&Ws[cbase + ((7 * 4 + kg) ^ cx) * 8]);

    f32x4 e0 = {0.f, 0.f, 0.f, 0.f}, e1 = {0.f, 0.f, 0.f, 0.f};
    f32x4 f0 = {0.f, 0.f, 0.f, 0.f}, f1 = {0.f, 0.f, 0.f, 0.f};
    e0 = __builtin_amdgcn_mfma_f32_16x16x32_f16(a0[0], b0, e0, 0, 0, 0);
    e1 = __builtin_amdgcn_mfma_f32_16x16x32_f16(a0[1], b1, e1, 0, 0, 0);
    f0 = __builtin_amdgcn_mfma_f32_16x16x32_f16(a1[0], b0, f0, 0, 0, 0);
    f1 = __builtin_amdgcn_mfma_f32_16x16x32_f16(a1[1], b1, f1, 0, 0, 0);
    e0 = __builtin_amdgcn_mfma_f32_16x16x32_f16(a0[2], b2, e0, 0, 0, 0);
    e1 = __builtin_amdgcn_mfma_f32_16x16x32_f16(a0[3], b3, e1, 0, 0, 0);
    f0 = __builtin_amdgcn_mfma_f32_16x16x32_f16(a1[2], b2, f0, 0, 0, 0);
    f1 = __builtin_amdgcn_mfma_f32_16x16x32_f16(a1[3], b3, f1, 0, 0, 0);
    e0 = __builtin_amdgcn_mfma_f32_16x16x32_f16(a0[4], b4, e0, 0, 0, 0);
    e1 = __builtin_amdgcn_mfma_f32_16x16x32_f16(a0[5], b5, e1, 0, 0, 0);
    f0 = __builtin_amdgcn_mfma_f32_16x16x32_f16(a1[4], b4, f0, 0, 0, 0);
    f1 = __builtin_amdgcn_mfma_f32_16x16x32_f16(a1[5], b5, f1, 0, 0, 0);
    e0 = __builtin_amdgcn_mfma_f32_16x16x32_f16(a0[6], b6, e0, 0, 0, 0);
    e1 = __builtin_amdgcn_mfma_f32_16x16x32_f16(a0[7], b7, e1, 0, 0, 0);
    f0 = __builtin_amdgcn_mfma_f32_16x16x32_f16(a1[6], b6, f0, 0, 0, 0);
    f1 = __builtin_amdgcn_mfma_f32_16x16x32_f16(a1[7], b7, f1, 0, 0, 0);
    f32x4 s0 = e0 + e1;
    f32x4 s1 = f0 + f1;
#pragma unroll
    for (int i = 0; i < 4; ++i) {
      if (orow0 + i < M)
        Zh[(size_t)(orow0 + i) * 256 + nf * 16 + r] = __float2half((float)s0[i]);
    }
#pragma unroll
    for (int i = 0; i < 4; ++i) {
      if (orow1 + i < M)
        Zh[(size_t)(orow1 + i) * 256 + nf * 16 + r] = __float2half((float)s1[i]);
    }
  }
}

// ---------------- GEMM2: Zh(Mx256,fp16) = H(Mx32) @ W2(32x256) ----------------
__global__ __launch_bounds__(256) void gemm_h_k(const float* __restrict__ Hmat,
                                                const float* __restrict__ W2,
                                                __half* __restrict__ Zh, int M) {
  __shared__ float Ws[32][256];
  __shared__ float Hs[32][20];
  int t = threadIdx.x;
  for (int i = t; i < 32 * 256; i += 256) Ws[i >> 8][i & 255] = W2[i];
  int row0 = blockIdx.x * 16;
  for (int i = t; i < 16 * 32; i += 256) {
    int r = i >> 5, k = i & 31;
    Hs[k][r] = (row0 + r < M) ? Hmat[(size_t)(row0 + r) * 32 + k] : 0.f;
  }
  __syncthreads();
  int tx = t & 63, ty = t >> 6;
  float acc[4][4] = {};
#pragma unroll
  for (int k = 0; k < 32; ++k) {
    float4 a4 = *reinterpret_cast<const float4*>(&Hs[k][ty * 4]);
    float4 b4 = *reinterpret_cast<const float4*>(&Ws[k][tx * 4]);
    float a[4] = {a4.x, a4.y, a4.z, a4.w};
    float b[4] = {b4.x, b4.y, b4.z, b4.w};
#pragma unroll
    for (int i = 0; i < 4; ++i)
#pragma unroll
      for (int j = 0; j < 4; ++j) acc[i][j] = fmaf(a[i], b[j], acc[i][j]);
  }
#pragma unroll
  for (int i = 0; i < 4; ++i) {
    int r = row0 + ty * 4 + i;
    if (r < M) {
      uint2 w;
      w.x = pkh2(acc[i][0], acc[i][1]);
      w.y = pkh2(acc[i][2], acc[i][3]);
      *reinterpret_cast<uint2*>(&Zh[(size_t)r * 256 + tx * 4]) = w;
    }
  }
}

// ---------------- attention logits (fp16 z) ----------------
__global__ __launch_bounds__(256) void logits_k(const __half* __restrict__ Zh,
                                                const float* __restrict__ al,
                                                const float* __restrict__ ar,
                                                float* __restrict__ el,
                                                float* __restrict__ er, int N) {
  int wave = threadIdx.x >> 6;
  int lane = threadIdx.x & 63;
  int n = blockIdx.x * 4 + wave;
  if (n >= N) return;
  uint2 u = *reinterpret_cast<const uint2*>(&Zh[(size_t)n * 256 + lane * 4]);
  float2 f0 = __half22float2(*reinterpret_cast<__half2*>(&u.x));
  float2 f1 = __half22float2(*reinterpret_cast<__half2*>(&u.y));
  float4 a4 = reinterpret_cast<const float4*>(al)[lane];
  float4 r4 = reinterpret_cast<const float4*>(ar)[lane];
  float pl = f0.x * a4.x + f0.y * a4.y + f1.x * a4.z + f1.y * a4.w;
  float pr = f0.x * r4.x + f0.y * r4.y + f1.x * r4.z + f1.y * r4.w;
  pl += __shfl_xor(pl, 1); pl += __shfl_xor(pl, 2); pl += __shfl_xor(pl, 4);
  pr += __shfl_xor(pr, 1); pr += __shfl_xor(pr, 2); pr += __shfl_xor(pr, 4);
  if ((lane & 7) == 0) {
    int h = lane >> 3;
    el[(size_t)n * 8 + h] = pl;
    er[(size_t)n * 8 + h] = pr;
  }
}

// ---------------- FUSED per-dst softmax + aggregation: one WAVE per dst ----------------
// Phase 1 (lane = h*8+es): max over edges, shfl-reduce within 8-lane es group.
// Phase 2 per 64-edge chunk: (2a) same lanes compute p=exp(e-m) -> LDS, s in reg;
// (2b) lanes as (h,q) gather z rows (512B/row) weighted by p from LDS.
// No __syncthreads (per-wave loops); wave-internal lgkmcnt drain between 2a/2b.
template <bool LAYER1>
__global__ __launch_bounds__(256) void aggf_k(const __half* __restrict__ Zh,
                                              const float* __restrict__ el,
                                              const float* __restrict__ er,
                                              const float* __restrict__ bias,
                                              const int* __restrict__ offs,
                                              const int* __restrict__ esrc,
                                              float* __restrict__ out, int N) {
  __shared__ float plds[4][64][8];  // [wave][edge-in-chunk][head], 8 KB
  int wid = threadIdx.x >> 6, lane = threadIdx.x & 63;
  int n = blockIdx.x * 4 + wid;
  if (n >= N) return;
  int h = lane >> 3;
  int sub = lane & 7;  // es in phase 1/2a, feature-quad q in phase 2b
  int beg = offs[n], end = offs[n + 1];
  float er_h = er[(size_t)n * 8 + h];

  // ---- phase 1: per-head max ----
  float m = -1e30f;
  for (int i = beg + sub; i < end; i += 8) {
    float e = el[(size_t)esrc[i] * 8 + h] + er_h;
    e = (e >= 0.f) ? e : 0.2f * e;
    m = fmaxf(m, e);
  }
  m = fmaxf(m, __shfl_xor(m, 1));
  m = fmaxf(m, __shfl_xor(m, 2));
  m = fmaxf(m, __shfl_xor(m, 4));

  // ---- phase 2: chunks of 64 edges ----
  float s = 0.f;
  float4 acc = make_float4(0.f, 0.f, 0.f, 0.f);
  for (int cbeg = beg; cbeg < end; cbeg += 64) {
    int cnt = min(64, end - cbeg);
    // 2a: p -> LDS
    for (int j = sub; j < cnt; j += 8) {
      float e = el[(size_t)esrc[cbeg + j] * 8 + h] + er_h;
      e = (e >= 0.f) ? e : 0.2f * e;
      float p = __expf(e - m);
      s += p;
      plds[wid][j][h] = p;
    }
    asm volatile("s_waitcnt lgkmcnt(0)" ::: "memory");
    __builtin_amdgcn_wave_barrier();
    // 2b: weighted z gather
    for (int j = 0; j < cnt; ++j) {
      int sidx = esrc[cbeg + j];
      float p = plds[wid][j][h];
      uint2 u = *reinterpret_cast<const uint2*>(&Zh[(size_t)sidx * 256 + h * 32 + sub * 4]);
      float2 f0 = __half22float2(*reinterpret_cast<__half2*>(&u.x));
      float2 f1 = __half22float2(*reinterpret_cast<__half2*>(&u.y));
      acc.x = fmaf(p, f0.x, acc.x);
      acc.y = fmaf(p, f0.y, acc.y);
      acc.z = fmaf(p, f1.x, acc.z);
      acc.w = fmaf(p, f1.y, acc.w);
    }
    __builtin_amdgcn_wave_barrier();
  }

  // ---- epilogue: normalize, bias, head-mean, (ELU) ----
  s += __shfl_xor(s, 1);
  s += __shfl_xor(s, 2);
  s += __shfl_xor(s, 4);
  float r = (end > beg) ? 1.f / s : 0.f;
  float4 b4 = *reinterpret_cast<const float4*>(&bias[h * 32 + sub * 4]);
  float4 v;
  v.x = fmaf(acc.x, r, b4.x);
  v.y = fmaf(acc.y, r, b4.y);
  v.z = fmaf(acc.z, r, b4.z);
  v.w = fmaf(acc.w, r, b4.w);
#pragma unroll
  for (int off = 8; off < 64; off <<= 1) {
    v.x += __shfl_xor(v.x, off);
    v.y += __shfl_xor(v.y, off);
    v.z += __shfl_xor(v.z, off);
    v.w += __shfl_xor(v.w, off);
  }
  if (h == 0) {
    v.x *= 0.125f; v.y *= 0.125f; v.z *= 0.125f; v.w *= 0.125f;
    if (LAYER1) {
      v.x = (v.x > 0.f) ? v.x : expm1f(v.x);
      v.y = (v.y > 0.f) ? v.y : expm1f(v.y);
      v.z = (v.z > 0.f) ? v.z : expm1f(v.z);
      v.w = (v.w > 0.f) ? v.w : expm1f(v.w);
    }
    *reinterpret_cast<float4*>(&out[(size_t)n * 32 + sub * 4]) = v;
  }
}

// ---------------- launch ----------------

extern "C" void kernel_launch(void* const* d_in, const int* in_sizes, int n_in,
                              void* d_out, int out_size, void* d_ws, size_t ws_size,
                              hipStream_t stream) {
  const float* x   = (const float*)d_in[0];
  const float* W1  = (const float*)d_in[1];
  const float* al1 = (const float*)d_in[2];
  const float* ar1 = (const float*)d_in[3];
  const float* b1  = (const float*)d_in[4];
  const float* W2  = (const float*)d_in[5];
  const float* al2 = (const float*)d_in[6];
  const float* ar2 = (const float*)d_in[7];
  const float* b2  = (const float*)d_in[8];
  const int* src   = (const int*)d_in[9];
  const int* dst   = (const int*)d_in[10];
  float* out = (float*)d_out;

  const int N = in_sizes[0] / IN_F;
  const int E = in_sizes[9];

  char* p = (char*)d_ws;
  auto alloc = [&](size_t bytes) {
    char* q = p;
    p += (bytes + 255) & ~(size_t)255;
    return q;
  };
  __half* zh  = (__half*)alloc((size_t)N * 256 * 2);  // z1 fp16, reused as z2
  __half* w1t = (__half*)alloc((size_t)256 * 256 * 2);
  float* el   = (float*)alloc((size_t)N * 8 * 4);
  float* er   = (float*)alloc((size_t)N * 8 * 4);
  float* h1   = (float*)alloc((size_t)N * 32 * 4);
  int* offs   = (int*)alloc((size_t)(N + 1) * 4);
  int* deg    = (int*)alloc((size_t)N * 4);
  int* cursor = (int*)alloc((size_t)N * 4);
  int* bsum   = (int*)alloc((size_t)SCAN_B * 4);
  int* esrc   = (int*)alloc((size_t)E * 4);

  hipMemsetAsync(deg, 0, (size_t)N * 4, stream);
  hipMemsetAsync(cursor, 0, (size_t)N * 4, stream);

  int nb = (N + SCAN_B - 1) / SCAN_B;
  hist_k<<<(E + 255) / 256, 256, 0, stream>>>(dst, deg, E);
  scan1_k<<<nb, SCAN_B, 0, stream>>>(deg, offs, bsum, N);
  scan2_k<<<1, SCAN_B, 0, stream>>>(bsum, nb);
  scan3_k<<<nb, SCAN_B, 0, stream>>>(offs, bsum, N);
  scatter_k<<<(E + 255) / 256, 256, 0, stream>>>(src, dst, offs, cursor, esrc, E);

  // ---- layer 1 ----
  w1cvt_k<<<dim3(16, 16), dim3(16, 16), 0, stream>>>(W1, w1t);
  gemm_xw_mfma_k<<<(N + 255) / 256, 512, 0, stream>>>(x, w1t, zh, N);
  logits_k<<<(N + 3) / 4, 256, 0, stream>>>(zh, al1, ar1, el, er, N);
  aggf_k<true><<<(N + 3) / 4, 256, 0, stream>>>(zh, el, er, b1, offs, esrc, h1, N);

  // ---- layer 2 ----
  gemm_h_k<<<(N + 15) / 16, 256, 0, stream>>>(h1, W2, zh, N);
  logits_k<<<(N + 3) / 4, 256, 0, stream>>>(zh, al2, ar2, el, er, N);
  aggf_k<false><<<(N + 3) / 4, 256, 0, stream>>>(zh, el, er, b2, offs, esrc, out, N);
}